// Round 7
// baseline (1057.656 us; speedup 1.0000x reference)
//
#include <hip/hip_runtime.h>
#include <cstdint>
#include <cstddef>

#define TSTEPS 1000
#define NB     256
#define NR     200
#define NI     10
#define ALPHA_F     0.1f
#define NOISE_STD_F 0.01f
#define ETA_STRIDE  (NB * NR)          // 51200 floats per timestep
#define ETA_FLOATS  ((size_t)TSTEPS * NB * NR)

// ---------------- JAX threefry2x32-20, key = (0, 42) --------------------
__device__ __forceinline__ uint32_t rotl32(uint32_t v, uint32_t d) {
  return (v << d) | (v >> (32u - d));
}

__device__ __forceinline__ uint32_t threefry_bits(uint32_t c1) {
  const uint32_t ks0 = 0u;
  const uint32_t ks1 = 42u;
  const uint32_t ks2 = 0x1BD11BDAu ^ ks0 ^ ks1;
  uint32_t x0 = ks0;
  uint32_t x1 = c1 + ks1;
#define TFR(r) { x0 += x1; x1 = rotl32(x1, (r)); x1 ^= x0; }
  TFR(13) TFR(15) TFR(26) TFR(6)   x0 += ks1; x1 += ks2 + 1u;
  TFR(17) TFR(29) TFR(16) TFR(24)  x0 += ks2; x1 += ks0 + 2u;
  TFR(13) TFR(15) TFR(26) TFR(6)   x0 += ks0; x1 += ks1 + 3u;
  TFR(17) TFR(29) TFR(16) TFR(24)  x0 += ks1; x1 += ks2 + 4u;
  TFR(13) TFR(15) TFR(26) TFR(6)   x0 += ks2; x1 += ks0 + 5u;
#undef TFR
  return x0 ^ x1;
}

// XLA ErfInv32 (Giles).
__device__ __forceinline__ float erfinv_f32(float x) {
  float w = -__logf(fmaf(-x, x, 1.0f));
  float p;
  if (w < 5.0f) {
    w = w - 2.5f;
    p = 2.81022636e-08f;
    p = fmaf(p, w, 3.43273939e-07f);
    p = fmaf(p, w, -3.5233877e-06f);
    p = fmaf(p, w, -4.39150654e-06f);
    p = fmaf(p, w, 0.00021858087f);
    p = fmaf(p, w, -0.00125372503f);
    p = fmaf(p, w, -0.00417768164f);
    p = fmaf(p, w, 0.246640727f);
    p = fmaf(p, w, 1.50140941f);
  } else {
    w = sqrtf(w) - 3.0f;
    p = -0.000200214257f;
    p = fmaf(p, w, 0.000100950558f);
    p = fmaf(p, w, 0.00134934322f);
    p = fmaf(p, w, -0.00367342844f);
    p = fmaf(p, w, 0.00573950773f);
    p = fmaf(p, w, -0.0076224613f);
    p = fmaf(p, w, 0.00943887047f);
    p = fmaf(p, w, 1.00167406f);
    p = fmaf(p, w, 2.83297682f);
  }
  return p * x;
}

__device__ __forceinline__ float jax_normal(uint32_t idx) {
  uint32_t bits = threefry_bits(idx);
  float f = __uint_as_float((bits >> 9) | 0x3F800000u) - 1.0f;  // [0,1)
  const float lo = -0.99999994f;                                 // nextafter(-1,0)
  float u = fmaf(f, 2.0f, lo);
  u = fmaxf(lo, u);
  return 1.41421356f * erfinv_f32(u);
}

// exp-based tanh: ~2ulp. tanh(y)=sign(y)*(1-t)/(1+t), t=exp(-2|y|).
__device__ __forceinline__ float tanh_fast(float y) {
  float ay = fabsf(y);
  float t  = __expf(-2.0f * ay);
  float r  = (1.0f - t) * __frcp_rn(1.0f + t);
  return copysignf(r, y);
}

// LDS-only barrier: orders DS ops without draining vmcnt (keeps global
// out-stores and eta/x pipeline loads in flight).
__device__ __forceinline__ void wg_barrier_lds() {
  asm volatile("s_waitcnt lgkmcnt(0)\n\ts_barrier" ::: "memory");
}

// ---------------- dense noise pre-generation (map kernel) ----------------
__launch_bounds__(256)
__global__ void noise_fill(float* __restrict__ ws) {
  const int64_t nq = (int64_t)ETA_FLOATS / 4;          // float4 groups
  const int64_t stride = (int64_t)gridDim.x * blockDim.x;
  for (int64_t i = (int64_t)blockIdx.x * blockDim.x + threadIdx.x;
       i < nq; i += stride) {
    uint32_t base = (uint32_t)(i * 4);
    float4 v;
    v.x = NOISE_STD_F * jax_normal(base + 0u);
    v.y = NOISE_STD_F * jax_normal(base + 1u);
    v.z = NOISE_STD_F * jax_normal(base + 2u);
    v.w = NOISE_STD_F * jax_normal(base + 3u);
    ((float4*)ws)[i] = v;
  }
}

// ============== R3-structure kernel, balanced phase B, reg-eta ==========
// 512 threads = 8 waves, 1 WG per batch, 256 WGs.
// Phase A (tid<500, ALL 8 waves): k=tid/50 in [0,10), r=tid%50 owns rows
//   4r..4r+3 x k-chunk [20k,20k+20); w[4][20]=80 floats/lane (proven
//   regalloc-safe). Partials -> LDS k-major float4 (conflict-free).
// Phase B:
//   UPD: waves 0-3, lanes 0-49 -> urow = wave*50+lane (one full update
//        wave per SIMD; consecutive partial reads, conflict-free).
//        eta is a PER-LANE register pipeline: use etaA/etaB, load
//        eta[t+2][urow] (coalesced b32, 2-step slack) issued FIRST so the
//        global load flies under the y-chain. No sh_eta at all.
//   x:   tid 448..457 (wave 7) float-per-thread LDS pipeline, 2-step slack.
template <int CUR, bool PF>
__device__ __forceinline__ void rnn_step(
    int t, int tid, bool mac_active, bool upd_lane, int urow,
    const float (&w)[4][20], const float (&winp)[NI], float brec_r,
    float& h_reg, float*& obp, float& xnA, float& xnB,
    float& etaA, float& etaB,
    const float* __restrict__ xb, const float* __restrict__ etab,
    const float* __restrict__ hp, float* __restrict__ part_wp,
    float* __restrict__ sh_h, float* __restrict__ sh_part,
    float (*__restrict__ sh_x)[16]) {
  constexpr int NXT = CUR ^ 1;

  // ---------- phase A: MACs from sh_h ----------
  if (mac_active) {
    float a0 = 0.0f, a1 = 0.0f, a2 = 0.0f, a3 = 0.0f;
#pragma unroll
    for (int q = 0; q < 5; ++q) {
      float4 hv = *(const float4*)(hp + 4 * q);
      a0 = fmaf(w[0][4 * q + 0], hv.x, a0);
      a1 = fmaf(w[1][4 * q + 0], hv.x, a1);
      a2 = fmaf(w[2][4 * q + 0], hv.x, a2);
      a3 = fmaf(w[3][4 * q + 0], hv.x, a3);
      a0 = fmaf(w[0][4 * q + 1], hv.y, a0);
      a1 = fmaf(w[1][4 * q + 1], hv.y, a1);
      a2 = fmaf(w[2][4 * q + 1], hv.y, a2);
      a3 = fmaf(w[3][4 * q + 1], hv.y, a3);
      a0 = fmaf(w[0][4 * q + 2], hv.z, a0);
      a1 = fmaf(w[1][4 * q + 2], hv.z, a1);
      a2 = fmaf(w[2][4 * q + 2], hv.z, a2);
      a3 = fmaf(w[3][4 * q + 2], hv.z, a3);
      a0 = fmaf(w[0][4 * q + 3], hv.w, a0);
      a1 = fmaf(w[1][4 * q + 3], hv.w, a1);
      a2 = fmaf(w[2][4 * q + 3], hv.w, a2);
      a3 = fmaf(w[3][4 * q + 3], hv.w, a3);
    }
    // k-major float4 write: conflict-free, 16B aligned (200%4==0)
    *(float4*)part_wp = make_float4(a0, a1, a2, a3);
  }
  wg_barrier_lds();

  // ---------- phase B ----------
  if (upd_lane) {
    // eta prefetch issued first: global load flies under the y-chain
    float e_new = 0.0f;
    if (PF) {
      int tf = t + 2;
      if (tf > TSTEPS - 1) tf = TSTEPS - 1;  // harmless redundant tail load
      e_new = etab[(size_t)tf * ETA_STRIDE + urow];
    }
    float y = brec_r;
#pragma unroll
    for (int q = 0; q < 10; ++q) y += sh_part[q * NR + urow];
    float4 xv0 = *(const float4*)(&sh_x[CUR][0]);
    float4 xv1 = *(const float4*)(&sh_x[CUR][4]);
    float2 xv2 = *(const float2*)(&sh_x[CUR][8]);
    y = fmaf(winp[0], xv0.x, y);
    y = fmaf(winp[1], xv0.y, y);
    y = fmaf(winp[2], xv0.z, y);
    y = fmaf(winp[3], xv0.w, y);
    y = fmaf(winp[4], xv1.x, y);
    y = fmaf(winp[5], xv1.y, y);
    y = fmaf(winp[6], xv1.z, y);
    y = fmaf(winp[7], xv1.w, y);
    y = fmaf(winp[8], xv2.x, y);
    y = fmaf(winp[9], xv2.y, y);
    float rate = tanh_fast(y);
    float eta  = (CUR == 0) ? etaA : etaB;
    float hn = h_reg + ALPHA_F * (((-h_reg) + rate) + eta);
    h_reg = hn;
    sh_h[urow] = hn;
    *obp = hn;
    obp += NR;
    if (PF) {
      if (CUR == 0) etaA = e_new; else etaB = e_new;
    }
  } else if (tid >= 448 && tid < 448 + NI) {
    if (PF) {
      int j = tid - 448;
      // write x(t+1), in flight for 2 steps -> no HBM stall here
      sh_x[NXT][j] = (CUR == 0) ? xnA : xnB;
      int tf = t + 3;
      if (tf > TSTEPS - 1) tf = TSTEPS - 1;
      float xl = xb[tf * NI + j];
      if (CUR == 0) xnA = xl; else xnB = xl;
    }
  }
  wg_barrier_lds();
}

__global__ __launch_bounds__(512, 2)
void rnn_persistent(const float* __restrict__ x,
                    const float* __restrict__ h0,
                    const float* __restrict__ Winp,
                    const float* __restrict__ Wrec,
                    const float* __restrict__ brec,
                    const float* __restrict__ eta_ws,
                    float* __restrict__ out) {
  const int b   = blockIdx.x;
  const int tid = threadIdx.x;
  const int wv  = tid >> 6;
  const int ln  = tid & 63;

  __shared__ float sh_h[NR];            // current hidden state
  __shared__ float sh_part[10 * NR];    // partials, k-major: [k*200 + row]
  __shared__ float sh_x[2][16];         // x_t double buffer

  const int  k_th = tid / 50;
  const int  r_th = tid % 50;
  const bool mac_active = (tid < 500);

  // UPD: waves 0-3, lanes 0-49 -> one full update wave per SIMD
  const bool upd_lane = (wv < 4) && (ln < 50);
  const int  urow     = wv * 50 + ln;              // valid iff upd_lane

  // --- stationary W_rec tile in registers (80 floats: proven safe) ---
  float w[4][20];
  if (mac_active) {
#pragma unroll
    for (int j = 0; j < 4; ++j) {
      const float* wr = Wrec + (size_t)(4 * r_th + j) * NR + 20 * k_th;
#pragma unroll
      for (int q = 0; q < 5; ++q) {
        float4 v = *(const float4*)(wr + 4 * q);
        w[j][4 * q + 0] = v.x; w[j][4 * q + 1] = v.y;
        w[j][4 * q + 2] = v.z; w[j][4 * q + 3] = v.w;
      }
    }
  }

  // --- update-lane state ---
  float winp[NI];
  float brec_r = 0.0f;
  float h_reg  = 0.0f;
  float etaA = 0.0f, etaB = 0.0f;
  float* obp   = nullptr;

  const float* xb   = x + (size_t)b * TSTEPS * NI;
  const float* etab = eta_ws + (size_t)b * NR;
  float* ob         = out + (size_t)b * TSTEPS * NR;

  if (upd_lane) {
#pragma unroll
    for (int i = 0; i < NI; ++i) winp[i] = Winp[urow * NI + i];
    brec_r = brec[urow];
    h_reg  = h0[(size_t)b * NR + urow];
    sh_h[urow] = h_reg;
    obp = ob + urow;
    etaA = etab[urow];                               // eta(0)
    etaB = etab[(size_t)1 * ETA_STRIDE + urow];      // eta(1)
  }

  float xnA = 0.0f, xnB = 0.0f;
  if (tid >= 448 && tid < 448 + NI) {
    int j = tid - 448;
    sh_x[0][j] = xb[j];          // x(0)
    xnA = xb[NI + j];            // x(1), consumed at t=0
    xnB = xb[2 * NI + j];        // x(2), consumed at t=1
  }
  __syncthreads();

  const float* hp      = sh_h + 20 * k_th;            // 16B aligned
  float*       part_wp = sh_part + k_th * NR + 4 * r_th;

  // main loop: unroll x2, compile-time buffer indices; tail peeled
  for (int t = 0; t < TSTEPS - 2; t += 2) {
    rnn_step<0, true>(t,     tid, mac_active, upd_lane, urow, w, winp, brec_r,
                      h_reg, obp, xnA, xnB, etaA, etaB, xb, etab, hp, part_wp,
                      sh_h, sh_part, sh_x);
    rnn_step<1, true>(t + 1, tid, mac_active, upd_lane, urow, w, winp, brec_r,
                      h_reg, obp, xnA, xnB, etaA, etaB, xb, etab, hp, part_wp,
                      sh_h, sh_part, sh_x);
  }
  rnn_step<0, true >(TSTEPS - 2, tid, mac_active, upd_lane, urow, w, winp,
                     brec_r, h_reg, obp, xnA, xnB, etaA, etaB, xb, etab, hp,
                     part_wp, sh_h, sh_part, sh_x);
  rnn_step<1, false>(TSTEPS - 1, tid, mac_active, upd_lane, urow, w, winp,
                     brec_r, h_reg, obp, xnA, xnB, etaA, etaB, xb, etab, hp,
                     part_wp, sh_h, sh_part, sh_x);
}

// ================== fallback: verified R1-style kernel ===================
// (in-kernel noise; used only if workspace is unavailable — 898 us rocprof.)
template <int CUR, bool PF>
__device__ __forceinline__ void fb_step(
    int t, int tid, bool mac_active,
    const float (&w)[4][20], const float (&winp)[NI], float brec_r,
    float& h_reg, float*& obp, float& xnA, float& xnB,
    const float* __restrict__ xb, uint32_t nb_b,
    const float* __restrict__ hp, float* __restrict__ part_wp,
    float* __restrict__ sh_h, float* __restrict__ sh_part,
    float (*__restrict__ sh_x)[16], float (*__restrict__ sh_eta)[NR]) {
  constexpr int NXT = CUR ^ 1;
  if (mac_active) {
    float a0 = 0.0f, a1 = 0.0f, a2 = 0.0f, a3 = 0.0f;
#pragma unroll
    for (int q = 0; q < 5; ++q) {
      float4 hv = *(const float4*)(hp + 4 * q);
      a0 = fmaf(w[0][4 * q + 0], hv.x, a0);
      a1 = fmaf(w[1][4 * q + 0], hv.x, a1);
      a2 = fmaf(w[2][4 * q + 0], hv.x, a2);
      a3 = fmaf(w[3][4 * q + 0], hv.x, a3);
      a0 = fmaf(w[0][4 * q + 1], hv.y, a0);
      a1 = fmaf(w[1][4 * q + 1], hv.y, a1);
      a2 = fmaf(w[2][4 * q + 1], hv.y, a2);
      a3 = fmaf(w[3][4 * q + 1], hv.y, a3);
      a0 = fmaf(w[0][4 * q + 2], hv.z, a0);
      a1 = fmaf(w[1][4 * q + 2], hv.z, a1);
      a2 = fmaf(w[2][4 * q + 2], hv.z, a2);
      a3 = fmaf(w[3][4 * q + 2], hv.z, a3);
      a0 = fmaf(w[0][4 * q + 3], hv.w, a0);
      a1 = fmaf(w[1][4 * q + 3], hv.w, a1);
      a2 = fmaf(w[2][4 * q + 3], hv.w, a2);
      a3 = fmaf(w[3][4 * q + 3], hv.w, a3);
    }
    *(float4*)part_wp = make_float4(a0, a1, a2, a3);
  }
  wg_barrier_lds();
  if (tid < NR) {
    float y = brec_r;
#pragma unroll
    for (int q = 0; q < 10; ++q) y += sh_part[q * NR + tid];
    float4 xv0 = *(const float4*)(&sh_x[CUR][0]);
    float4 xv1 = *(const float4*)(&sh_x[CUR][4]);
    float2 xv2 = *(const float2*)(&sh_x[CUR][8]);
    y = fmaf(winp[0], xv0.x, y);
    y = fmaf(winp[1], xv0.y, y);
    y = fmaf(winp[2], xv0.z, y);
    y = fmaf(winp[3], xv0.w, y);
    y = fmaf(winp[4], xv1.x, y);
    y = fmaf(winp[5], xv1.y, y);
    y = fmaf(winp[6], xv1.z, y);
    y = fmaf(winp[7], xv1.w, y);
    y = fmaf(winp[8], xv2.x, y);
    y = fmaf(winp[9], xv2.y, y);
    float rate = tanh_fast(y);
    float eta  = sh_eta[CUR][tid];
    float hn = h_reg + ALPHA_F * (((-h_reg) + rate) + eta);
    h_reg = hn;
    sh_h[tid] = hn;
    *obp = hn;
    obp += NR;
  } else if ((tid >= 256 && tid < 448) || (tid < 208)) {
    if (PF) {
      int n = (tid >= 256) ? (tid - 256) : (tid - 8);
      uint32_t idx = (uint32_t)(t + 1) * (uint32_t)(NB * NR) + nb_b + (uint32_t)n;
      sh_eta[NXT][n] = NOISE_STD_F * jax_normal(idx);
    }
  } else if (tid >= 448 && tid < 448 + NI) {
    if (PF) {
      int j = tid - 448;
      sh_x[NXT][j] = (CUR == 0) ? xnA : xnB;
      int tf = t + 3;
      if (tf > TSTEPS - 1) tf = TSTEPS - 1;
      float xl = xb[tf * NI + j];
      if (CUR == 0) xnA = xl; else xnB = xl;
    }
  }
  wg_barrier_lds();
}

__global__ __launch_bounds__(512, 2)
void rnn_fallback(const float* __restrict__ x,
                  const float* __restrict__ h0,
                  const float* __restrict__ Winp,
                  const float* __restrict__ Wrec,
                  const float* __restrict__ brec,
                  float* __restrict__ out) {
  const int b   = blockIdx.x;
  const int tid = threadIdx.x;
  __shared__ float sh_h[NR];
  __shared__ float sh_part[10 * NR];
  __shared__ float sh_x[2][16];
  __shared__ float sh_eta[2][NR];
  const int  k_th = tid / 50;
  const int  r_th = tid % 50;
  const bool mac_active = (tid < 500);
  float w[4][20];
  if (mac_active) {
#pragma unroll
    for (int j = 0; j < 4; ++j) {
      const float* wr = Wrec + (size_t)(4 * r_th + j) * NR + 20 * k_th;
#pragma unroll
      for (int q = 0; q < 5; ++q) {
        float4 v = *(const float4*)(wr + 4 * q);
        w[j][4 * q + 0] = v.x; w[j][4 * q + 1] = v.y;
        w[j][4 * q + 2] = v.z; w[j][4 * q + 3] = v.w;
      }
    }
  }
  float winp[NI];
  float brec_r = 0.0f, h_reg = 0.0f;
  float* obp = nullptr;
  const float* xb = x + (size_t)b * TSTEPS * NI;
  float* ob       = out + (size_t)b * TSTEPS * NR;
  if (tid < NR) {
#pragma unroll
    for (int i = 0; i < NI; ++i) winp[i] = Winp[tid * NI + i];
    brec_r = brec[tid];
    h_reg  = h0[(size_t)b * NR + tid];
    sh_h[tid] = h_reg;
    obp = ob + tid;
  }
  const uint32_t nb_b = (uint32_t)b * (uint32_t)NR;
  float xnA = 0.0f, xnB = 0.0f;
  if ((tid >= 256 && tid < 448) || (tid >= 200 && tid < 208)) {
    int n = (tid >= 256) ? (tid - 256) : (tid - 8);
    sh_eta[0][n] = NOISE_STD_F * jax_normal(nb_b + (uint32_t)n);
  }
  if (tid >= 448 && tid < 448 + NI) {
    int j = tid - 448;
    sh_x[0][j] = xb[j];
    xnA = xb[NI + j];
    xnB = xb[2 * NI + j];
  }
  __syncthreads();
  const float* hp      = sh_h + 20 * k_th;
  float*       part_wp = sh_part + k_th * NR + 4 * r_th;
  for (int t = 0; t < TSTEPS - 2; t += 2) {
    fb_step<0, true>(t,     tid, mac_active, w, winp, brec_r, h_reg, obp,
                     xnA, xnB, xb, nb_b, hp, part_wp, sh_h, sh_part, sh_x, sh_eta);
    fb_step<1, true>(t + 1, tid, mac_active, w, winp, brec_r, h_reg, obp,
                     xnA, xnB, xb, nb_b, hp, part_wp, sh_h, sh_part, sh_x, sh_eta);
  }
  fb_step<0, true >(TSTEPS - 2, tid, mac_active, w, winp, brec_r, h_reg, obp,
                    xnA, xnB, xb, nb_b, hp, part_wp, sh_h, sh_part, sh_x, sh_eta);
  fb_step<1, false>(TSTEPS - 1, tid, mac_active, w, winp, brec_r, h_reg, obp,
                    xnA, xnB, xb, nb_b, hp, part_wp, sh_h, sh_part, sh_x, sh_eta);
}

extern "C" void kernel_launch(void* const* d_in, const int* in_sizes, int n_in,
                              void* d_out, int out_size, void* d_ws, size_t ws_size,
                              hipStream_t stream) {
  const float* x    = (const float*)d_in[0];  // [256,1000,10]
  const float* h0   = (const float*)d_in[1];  // [256,200]
  const float* Winp = (const float*)d_in[2];  // [200,10]
  const float* Wrec = (const float*)d_in[3];  // [200,200]
  const float* brec = (const float*)d_in[4];  // [200]
  float* out = (float*)d_out;                 // [256,1000,200]
  (void)in_sizes; (void)n_in; (void)out_size;

  const size_t eta_bytes = ETA_FLOATS * sizeof(float);  // 204.8 MB
  if (d_ws != nullptr && ws_size >= eta_bytes) {
    noise_fill<<<dim3(4096), dim3(256), 0, stream>>>((float*)d_ws);
    rnn_persistent<<<dim3(NB), dim3(512), 0, stream>>>(
        x, h0, Winp, Wrec, brec, (const float*)d_ws, out);
  } else {
    rnn_fallback<<<dim3(NB), dim3(512), 0, stream>>>(
        x, h0, Winp, Wrec, brec, out);
  }
}